// Round 1
// 698.446 us; speedup vs baseline: 1.0977x; 1.0977x over previous
//
#include <hip/hip_runtime.h>

typedef float    floatx4 __attribute__((ext_vector_type(4)));
typedef short    short8  __attribute__((ext_vector_type(8)));
typedef _Float16 h4      __attribute__((ext_vector_type(4)));

#define NROWS 32768   // B*S
#define KD    1024    // 2*D == N
#define DD    512

// pack two fp32 (bit patterns) -> dword of two bf16 (truncation), lo element in low half
__device__ __forceinline__ unsigned pk_bf16(unsigned hi_bits, unsigned lo_bits) {
    return __builtin_amdgcn_perm(hi_bits, lo_bits, 0x07060302u);
}

__device__ __forceinline__ void gload_lds16(const void* g, void* l) {
    __builtin_amdgcn_global_load_lds((__attribute__((address_space(1))) void*)(void*)g,
                                     (__attribute__((address_space(3))) void*)l,
                                     16, 0, 0);
}

// ---------------- k_row: |z|^2 row sums, |z| row sums, and z_flat -> bf16 [row][1024] -----
__global__ void k_row(const float* __restrict__ zr, const float* __restrict__ zi,
                      unsigned short* __restrict__ zb,
                      float* __restrict__ zz, float* __restrict__ mgp) {
    int r = blockIdx.x, t = threadIdx.x;
    const float2* a2 = (const float2*)(zr + (size_t)r * DD);
    const float2* b2 = (const float2*)(zi + (size_t)r * DD);
    float2 a = a2[t], b = b2[t];
    unsigned* zrow = (unsigned*)(zb + (size_t)r * KD);
    zrow[t]       = pk_bf16(__float_as_uint(a.y), __float_as_uint(a.x));
    zrow[256 + t] = pk_bf16(__float_as_uint(b.y), __float_as_uint(b.x));
    float m0 = a.x * a.x + b.x * b.x;
    float m1 = a.y * a.y + b.y * b.y;
    float sm2 = m0 + m1;
    float smg = sqrtf(m0) + sqrtf(m1);
    for (int o = 32; o > 0; o >>= 1) { sm2 += __shfl_down(sm2, o); smg += __shfl_down(smg, o); }
    __shared__ float r2[4], rg[4];
    int wv = t >> 6, ln = t & 63;
    if (ln == 0) { r2[wv] = sm2; rg[wv] = smg; }
    __syncthreads();
    if (t == 0) {
        zz[r]  = r2[0] + r2[1] + r2[2] + r2[3];
        mgp[r] = rg[0] + rg[1] + rg[2] + rg[3];
    }
}

// ---------------- k_prev: prev fp32 -> bf16, streaming --------------------------------------
__global__ void k_prev(const float* __restrict__ p, unsigned short* __restrict__ pb) {
    size_t i = ((size_t)blockIdx.x * 256 + threadIdx.x) * 8;
    const uint4* g = (const uint4*)(p + i);
    uint4 u0 = g[0], u1 = g[1];
    uint4 o;
    o.x = pk_bf16(u0.y, u0.x); o.y = pk_bf16(u0.w, u0.z);
    o.z = pk_bf16(u1.y, u1.x); o.w = pk_bf16(u1.w, u1.z);
    *(uint4*)(pb + i) = o;
}

// ---------------- k_cb: codebook fp32 [n][k] -> bf16 [n][k], cc[n] = sum_k c^2 ------------
__global__ void k_cb(const float* __restrict__ cb, unsigned short* __restrict__ cb_bf,
                     float* __restrict__ cc) {
    int n = blockIdx.x, t = threadIdx.x;
    const float4* src = (const float4*)(cb + (size_t)n * KD);
    float4 v = src[t];
    float s = v.x * v.x + v.y * v.y + v.z * v.z + v.w * v.w;
    unsigned d0 = pk_bf16(__float_as_uint(v.y), __float_as_uint(v.x));
    unsigned d1 = pk_bf16(__float_as_uint(v.w), __float_as_uint(v.z));
    *(uint2*)(cb_bf + (size_t)n * KD + t * 4) = make_uint2(d0, d1);
    for (int o = 32; o > 0; o >>= 1) s += __shfl_down(s, o);
    __shared__ float rd[4];
    int wv = t >> 6, ln = t & 63;
    if (ln == 0) rd[wv] = s;
    __syncthreads();
    if (t == 0) cc[n] = rd[0] + rd[1] + rd[2] + rd[3];
}

// ---------------- k_tr: dst[c][r] = bf16(src[r][c]), 1024x1024 ----------------------------
__global__ void k_tr(const float* __restrict__ src, unsigned short* __restrict__ dst) {
    __shared__ float tile[32][33];
    int bx = blockIdx.x * 32, by = blockIdx.y * 32;
    int tx = threadIdx.x, ty = threadIdx.y;   // (32,8)
    for (int r = ty; r < 32; r += 8)
        tile[r][tx] = src[(size_t)(by + r) * 1024 + bx + tx];
    __syncthreads();
    for (int r = ty; r < 32; r += 8)
        dst[(size_t)(bx + r) * 1024 + by + tx] =
            (unsigned short)(__float_as_uint(tile[tx][r]) >> 16);
}

// ---------------- k_scalar: var -> lam = 0.1*softplus(var/(1+eps)); sums[1] = sum|z|^2 ----
__global__ void k_scalar(const float* __restrict__ zz, const float* __restrict__ mgp,
                         double* __restrict__ sums, float* __restrict__ lam) {
    int t = threadIdx.x;  // 1024
    double s2 = 0.0, sg = 0.0;
    for (int i = t; i < NROWS; i += 1024) { s2 += (double)zz[i]; sg += (double)mgp[i]; }
    __shared__ double l2[1024], lg[1024];
    l2[t] = s2; lg[t] = sg; __syncthreads();
    for (int s = 512; s > 0; s >>= 1) {
        if (t < s) { l2[t] += l2[t + s]; lg[t] += lg[t + s]; }
        __syncthreads();
    }
    if (t == 0) {
        double M = 16777216.0;
        double var = (l2[0] - lg[0] * lg[0] / M) / (M - 1.0);
        double x = var / (1.0 + 1e-6);
        double mod = log1p(exp(x));
        lam[0] = (float)(0.1 * mod);
        sums[1] = l2[0];
    }
}

// ---------------- k_gemm12: dual GEMM, BK=64, swizzled LDS, XCD-remapped ------------------
// LDS tiles are [128 rows][64 cols] bf16 (128B row stride), linear in 16B granule index
// g = row*8 + slot. global_load_lds writes linearly, so the bank swizzle is applied by
// fetching granule (r, slot) from global column ((slot ^ (r&7))<<3) and reading fragments
// at slot' = slot ^ (r&7)  (both-sides rule: source perm == read perm, an involution).
__global__ __launch_bounds__(512, 4)
void k_gemm12(const unsigned short* __restrict__ zb,
              const unsigned short* __restrict__ pb,
              const unsigned short* __restrict__ cb_bf,
              const unsigned short* __restrict__ adjT_bf,
              const float* __restrict__ cc, const float* __restrict__ lam_p,
              _Float16* __restrict__ s_out, double* __restrict__ e_acc) {
    __shared__ unsigned short A1[128 * 64], A2[128 * 64], B1[128 * 64], B2[128 * 64];
    int tid = threadIdx.x, bid = blockIdx.x;
    // XCD-aware remap (nwg=2048 % 8 == 0 -> simple bijective form): each XCD sweeps
    // all 8 col-tiles of a row-tile consecutively -> A row-tile stays in its L2.
    int wg = (bid & 7) * 256 + (bid >> 3);
    int rt = wg >> 3, ct = wg & 7;
    int row0 = rt * 128, col0 = ct * 128;
    int wv = tid >> 6, ln = tid & 63;
    int wr = (wv >> 1) * 32;   // wave rows: 0,32,64,96
    int wc = (wv & 1) * 64;    // wave cols: 0,64

    floatx4 acc1[2][4], acc2[2][4];
    for (int i = 0; i < 2; ++i)
        for (int j = 0; j < 4; ++j) {
            floatx4 z4 = {0.f, 0.f, 0.f, 0.f};
            acc1[i][j] = z4; acc2[i][j] = z4;
        }

    // staging: 1024 granules per tile, 2 per thread. call0: g=tid, call1: g=512+tid.
    int r0 = tid >> 3,         s0 = tid & 7;
    int r1 = (512 + tid) >> 3; // slot of call1 is also tid&7
    size_t aoff0 = (size_t)(row0 + r0) * KD + ((s0 ^ (r0 & 7)) << 3);
    size_t aoff1 = (size_t)(row0 + r1) * KD + ((s0 ^ (r1 & 7)) << 3);
    size_t boff0 = (size_t)(col0 + r0) * KD + ((s0 ^ (r0 & 7)) << 3);
    size_t boff1 = (size_t)(col0 + r1) * KD + ((s0 ^ (r1 & 7)) << 3);
    int l0 = wv * 512;          // wave-uniform LDS dest (elements), call 0
    int l1 = 4096 + wv * 512;   // call 1

    for (int kb = 0; kb < KD; kb += 64) {
        gload_lds16(zb      + aoff0 + kb, &A1[l0]);
        gload_lds16(zb      + aoff1 + kb, &A1[l1]);
        gload_lds16(pb      + aoff0 + kb, &A2[l0]);
        gload_lds16(pb      + aoff1 + kb, &A2[l1]);
        gload_lds16(cb_bf   + boff0 + kb, &B1[l0]);
        gload_lds16(cb_bf   + boff1 + kb, &B1[l1]);
        gload_lds16(adjT_bf + boff0 + kb, &B2[l0]);
        gload_lds16(adjT_bf + boff1 + kb, &B2[l1]);
        __syncthreads();

        #pragma unroll
        for (int kk = 0; kk < 2; ++kk) {
            int sb = kk * 4 + (ln >> 4);   // un-swizzled 16B slot of this fragment
            short8 af[2], bfr[4];
            #pragma unroll
            for (int i = 0; i < 2; ++i) {
                int r = wr + i * 16 + (ln & 15);
                af[i] = *(const short8*)&A1[r * 64 + ((sb ^ (r & 7)) << 3)];
            }
            #pragma unroll
            for (int j = 0; j < 4; ++j) {
                int r = wc + j * 16 + (ln & 15);
                bfr[j] = *(const short8*)&B1[r * 64 + ((sb ^ (r & 7)) << 3)];
            }
            #pragma unroll
            for (int mi = 0; mi < 2; ++mi)
                #pragma unroll
                for (int ni = 0; ni < 4; ++ni)
                    acc1[mi][ni] = __builtin_amdgcn_mfma_f32_16x16x32_bf16(af[mi], bfr[ni], acc1[mi][ni], 0, 0, 0);
            #pragma unroll
            for (int i = 0; i < 2; ++i) {
                int r = wr + i * 16 + (ln & 15);
                af[i] = *(const short8*)&A2[r * 64 + ((sb ^ (r & 7)) << 3)];
            }
            #pragma unroll
            for (int j = 0; j < 4; ++j) {
                int r = wc + j * 16 + (ln & 15);
                bfr[j] = *(const short8*)&B2[r * 64 + ((sb ^ (r & 7)) << 3)];
            }
            #pragma unroll
            for (int mi = 0; mi < 2; ++mi)
                #pragma unroll
                for (int ni = 0; ni < 4; ++ni)
                    acc2[mi][ni] = __builtin_amdgcn_mfma_f32_16x16x32_bf16(af[mi], bfr[ni], acc2[mi][ni], 0, 0, 0);
        }
        __syncthreads();
    }

    // epilogue: s = (cc - 2*dot)/1024 - lam*sigmoid(gb); store fp16; energy partial
    float lam = *lam_p;
    float esum = 0.f;
    for (int mi = 0; mi < 2; ++mi) {
        int rbase = row0 + wr + mi * 16 + (ln >> 4) * 4;
        for (int ni = 0; ni < 4; ++ni) {
            int col = col0 + wc + ni * 16 + (ln & 15);
            float ccol = cc[col];
            for (int r2 = 0; r2 < 4; ++r2) {
                float d1 = acc1[mi][ni][r2];
                float d2 = acc2[mi][ni][r2];
                float sv = (ccol - 2.f * d1) * (1.0f / 1024.0f) - lam / (1.f + __expf(-d2));
                esum += sv;
                s_out[(size_t)(rbase + r2) * KD + col] = (_Float16)sv;
            }
        }
    }
    for (int o = 32; o > 0; o >>= 1) esum += __shfl_down(esum, o);
    if (ln == 0) atomicAdd(e_acc, (double)esum);
}

// ---------------- k_softmax: probs = softmax(-s) rowwise; in-place fp16 -> bf16 -----------
__global__ void k_softmax(_Float16* __restrict__ sp) {
    int row = blockIdx.x, t = threadIdx.x;
    int wv = t >> 6, ln = t & 63;
    _Float16* srow = sp + (size_t)row * KD;
    h4 v = *(const h4*)(srow + t * 4);
    float x0 = -(float)v.x, x1 = -(float)v.y, x2 = -(float)v.z, x3 = -(float)v.w;
    float mx = fmaxf(fmaxf(x0, x1), fmaxf(x2, x3));
    for (int o = 1; o < 64; o <<= 1) mx = fmaxf(mx, __shfl_xor(mx, o));
    __shared__ float redm[4];
    if (ln == 0) redm[wv] = mx;
    __syncthreads();
    mx = fmaxf(fmaxf(redm[0], redm[1]), fmaxf(redm[2], redm[3]));
    float e0 = __expf(x0 - mx), e1 = __expf(x1 - mx), e2 = __expf(x2 - mx), e3 = __expf(x3 - mx);
    float ss = e0 + e1 + e2 + e3;
    for (int o = 1; o < 64; o <<= 1) ss += __shfl_xor(ss, o);
    __shared__ float reds[4];
    if (ln == 0) reds[wv] = ss;
    __syncthreads();
    ss = reds[0] + reds[1] + reds[2] + reds[3];
    float inv = 1.f / ss;
    unsigned p0 = __float_as_uint(e0 * inv), p1 = __float_as_uint(e1 * inv);
    unsigned p2 = __float_as_uint(e2 * inv), p3 = __float_as_uint(e3 * inv);
    *(uint2*)((unsigned short*)srow + t * 4) = make_uint2(pk_bf16(p1, p0), pk_bf16(p3, p2));
}

// ---------------- k_gemm3: z_q = probs @ codebook (via codebook^T), BK=64 swizzled --------
__global__ __launch_bounds__(512, 4)
void k_gemm3(const unsigned short* __restrict__ probs,
             const unsigned short* __restrict__ cbT_bf,
             float* __restrict__ outR, float* __restrict__ outI) {
    __shared__ unsigned short At[128 * 64], Bt[128 * 64];
    int tid = threadIdx.x, bid = blockIdx.x;
    int wg = (bid & 7) * 256 + (bid >> 3);
    int rt = wg >> 3, ct = wg & 7;
    int row0 = rt * 128, col0 = ct * 128;
    int wv = tid >> 6, ln = tid & 63;
    int wr = (wv >> 1) * 32;
    int wc = (wv & 1) * 64;

    floatx4 acc[2][4];
    for (int i = 0; i < 2; ++i)
        for (int j = 0; j < 4; ++j) { floatx4 z4 = {0.f, 0.f, 0.f, 0.f}; acc[i][j] = z4; }

    int r0 = tid >> 3,         s0 = tid & 7;
    int r1 = (512 + tid) >> 3;
    size_t aoff0 = (size_t)(row0 + r0) * KD + ((s0 ^ (r0 & 7)) << 3);
    size_t aoff1 = (size_t)(row0 + r1) * KD + ((s0 ^ (r1 & 7)) << 3);
    size_t boff0 = (size_t)(col0 + r0) * KD + ((s0 ^ (r0 & 7)) << 3);
    size_t boff1 = (size_t)(col0 + r1) * KD + ((s0 ^ (r1 & 7)) << 3);
    int l0 = wv * 512;
    int l1 = 4096 + wv * 512;

    for (int kb = 0; kb < KD; kb += 64) {
        gload_lds16(probs  + aoff0 + kb, &At[l0]);
        gload_lds16(probs  + aoff1 + kb, &At[l1]);
        gload_lds16(cbT_bf + boff0 + kb, &Bt[l0]);
        gload_lds16(cbT_bf + boff1 + kb, &Bt[l1]);
        __syncthreads();

        #pragma unroll
        for (int kk = 0; kk < 2; ++kk) {
            int sb = kk * 4 + (ln >> 4);
            short8 af[2], bfr[4];
            #pragma unroll
            for (int i = 0; i < 2; ++i) {
                int r = wr + i * 16 + (ln & 15);
                af[i] = *(const short8*)&At[r * 64 + ((sb ^ (r & 7)) << 3)];
            }
            #pragma unroll
            for (int j = 0; j < 4; ++j) {
                int r = wc + j * 16 + (ln & 15);
                bfr[j] = *(const short8*)&Bt[r * 64 + ((sb ^ (r & 7)) << 3)];
            }
            #pragma unroll
            for (int mi = 0; mi < 2; ++mi)
                #pragma unroll
                for (int ni = 0; ni < 4; ++ni)
                    acc[mi][ni] = __builtin_amdgcn_mfma_f32_16x16x32_bf16(af[mi], bfr[ni], acc[mi][ni], 0, 0, 0);
        }
        __syncthreads();
    }

    for (int mi = 0; mi < 2; ++mi) {
        int rbase = row0 + wr + mi * 16 + (ln >> 4) * 4;
        for (int ni = 0; ni < 4; ++ni) {
            int col = col0 + wc + ni * 16 + (ln & 15);
            for (int r2 = 0; r2 < 4; ++r2) {
                float v = acc[mi][ni][r2];
                size_t row = (size_t)(rbase + r2);
                if (col < DD) outR[row * DD + col] = v;
                else          outI[row * DD + (col - DD)] = v;
            }
        }
    }
}

// ---------------- k_final: energy = (sum_s + sum|z|^2) / (M*N) ----------------------------
__global__ void k_final(const double* __restrict__ sums, float* __restrict__ outE) {
    outE[0] = (float)((sums[0] + sums[1]) / 33554432.0);
}

extern "C" void kernel_launch(void* const* d_in, const int* in_sizes, int n_in,
                              void* d_out, int out_size, void* d_ws, size_t ws_size,
                              hipStream_t stream) {
    const float* zr   = (const float*)d_in[0];
    const float* zi   = (const float*)d_in[1];
    const float* prev = (const float*)d_in[2];
    const float* cb   = (const float*)d_in[3];
    const float* adj  = (const float*)d_in[4];
    float* out  = (float*)d_out;
    float* outR = out;
    float* outI = out + (size_t)16777216;
    float* outE = out + (size_t)33554432;

    // zb/pb live in d_out: consumed by k_gemm12, dead before k_gemm3 overwrites d_out.
    unsigned short* zb = (unsigned short*)d_out;                        // [32768][1024] bf16
    unsigned short* pb = (unsigned short*)d_out + (size_t)33554432;     // [32768][1024] bf16

    char* ws = (char*)d_ws;
    double* sums          = (double*)ws;                       // [0]=energy acc, [1]=sum|z|^2
    float*  lam           = (float*)(ws + 16);
    float*  zz            = (float*)(ws + 256);                // [32768]
    float*  mgp           = (float*)(ws + 131328);             // [32768]
    float*  cc            = (float*)(ws + 262400);             // [1024]
    unsigned short* cb_bf = (unsigned short*)(ws + 266496);    // [1024*1024] bf16
    unsigned short* adjT  = (unsigned short*)(ws + 2363648);   // [1024*1024] bf16 (transposed)
    unsigned short* cbT   = (unsigned short*)(ws + 4460800);   // [1024*1024] bf16 (transposed)
    _Float16*       sbuf  = (_Float16*)(ws + 6557952);         // [32768*1024] fp16 logits -> bf16 probs

    hipMemsetAsync(d_ws, 0, 32, stream);
    k_row<<<32768, 256, 0, stream>>>(zr, zi, zb, zz, mgp);
    k_prev<<<16384, 256, 0, stream>>>(prev, pb);
    k_cb<<<1024, 256, 0, stream>>>(cb, cb_bf, cc);
    k_tr<<<dim3(32, 32), dim3(32, 8), 0, stream>>>(adj, adjT);
    k_tr<<<dim3(32, 32), dim3(32, 8), 0, stream>>>(cb, cbT);
    k_scalar<<<1, 1024, 0, stream>>>(zz, mgp, sums, lam);
    k_gemm12<<<2048, 512, 0, stream>>>(zb, pb, cb_bf, adjT, cc, lam, sbuf, sums);
    k_softmax<<<32768, 256, 0, stream>>>(sbuf);
    k_gemm3<<<2048, 512, 0, stream>>>((const unsigned short*)sbuf, cbT, outR, outI);
    k_final<<<1, 1, 0, stream>>>(sums, outE);
}

// Round 2
// 646.053 us; speedup vs baseline: 1.1868x; 1.0811x over previous
//
#include <hip/hip_runtime.h>

typedef float    floatx4 __attribute__((ext_vector_type(4)));
typedef short    short8  __attribute__((ext_vector_type(8)));
typedef _Float16 h4      __attribute__((ext_vector_type(4)));

#define NROWS 32768   // B*S
#define KD    1024    // 2*D == N
#define DD    512

// pack two fp32 (bit patterns) -> dword of two bf16 (truncation), lo element in low half
__device__ __forceinline__ unsigned pk_bf16(unsigned hi_bits, unsigned lo_bits) {
    return __builtin_amdgcn_perm(hi_bits, lo_bits, 0x07060302u);
}

__device__ __forceinline__ void gload_lds16(const void* g, void* l) {
    __builtin_amdgcn_global_load_lds((__attribute__((address_space(1))) void*)(void*)g,
                                     (__attribute__((address_space(3))) void*)l,
                                     16, 0, 0);
}

// ---------------- k_row: |z|^2 row sums, |z| row sums, and z_flat -> bf16 [row][1024] -----
__global__ void k_row(const float* __restrict__ zr, const float* __restrict__ zi,
                      unsigned short* __restrict__ zb,
                      float* __restrict__ zz, float* __restrict__ mgp) {
    int r = blockIdx.x, t = threadIdx.x;
    const float2* a2 = (const float2*)(zr + (size_t)r * DD);
    const float2* b2 = (const float2*)(zi + (size_t)r * DD);
    float2 a = a2[t], b = b2[t];
    unsigned* zrow = (unsigned*)(zb + (size_t)r * KD);
    zrow[t]       = pk_bf16(__float_as_uint(a.y), __float_as_uint(a.x));
    zrow[256 + t] = pk_bf16(__float_as_uint(b.y), __float_as_uint(b.x));
    float m0 = a.x * a.x + b.x * b.x;
    float m1 = a.y * a.y + b.y * b.y;
    float sm2 = m0 + m1;
    float smg = sqrtf(m0) + sqrtf(m1);
    for (int o = 32; o > 0; o >>= 1) { sm2 += __shfl_down(sm2, o); smg += __shfl_down(smg, o); }
    __shared__ float r2[4], rg[4];
    int wv = t >> 6, ln = t & 63;
    if (ln == 0) { r2[wv] = sm2; rg[wv] = smg; }
    __syncthreads();
    if (t == 0) {
        zz[r]  = r2[0] + r2[1] + r2[2] + r2[3];
        mgp[r] = rg[0] + rg[1] + rg[2] + rg[3];
    }
}

// ---------------- k_prev: prev fp32 -> bf16, streaming --------------------------------------
__global__ void k_prev(const float* __restrict__ p, unsigned short* __restrict__ pb) {
    size_t i = ((size_t)blockIdx.x * 256 + threadIdx.x) * 8;
    const uint4* g = (const uint4*)(p + i);
    uint4 u0 = g[0], u1 = g[1];
    uint4 o;
    o.x = pk_bf16(u0.y, u0.x); o.y = pk_bf16(u0.w, u0.z);
    o.z = pk_bf16(u1.y, u1.x); o.w = pk_bf16(u1.w, u1.z);
    *(uint4*)(pb + i) = o;
}

// ---------------- k_cb: codebook fp32 [n][k] -> bf16 [n][k], cc[n] = sum_k c^2 ------------
__global__ void k_cb(const float* __restrict__ cb, unsigned short* __restrict__ cb_bf,
                     float* __restrict__ cc) {
    int n = blockIdx.x, t = threadIdx.x;
    const float4* src = (const float4*)(cb + (size_t)n * KD);
    float4 v = src[t];
    float s = v.x * v.x + v.y * v.y + v.z * v.z + v.w * v.w;
    unsigned d0 = pk_bf16(__float_as_uint(v.y), __float_as_uint(v.x));
    unsigned d1 = pk_bf16(__float_as_uint(v.w), __float_as_uint(v.z));
    *(uint2*)(cb_bf + (size_t)n * KD + t * 4) = make_uint2(d0, d1);
    for (int o = 32; o > 0; o >>= 1) s += __shfl_down(s, o);
    __shared__ float rd[4];
    int wv = t >> 6, ln = t & 63;
    if (ln == 0) rd[wv] = s;
    __syncthreads();
    if (t == 0) cc[n] = rd[0] + rd[1] + rd[2] + rd[3];
}

// ---------------- k_tr: dst[c][r] = bf16(src[r][c]), 1024x1024 ----------------------------
__global__ void k_tr(const float* __restrict__ src, unsigned short* __restrict__ dst) {
    __shared__ float tile[32][33];
    int bx = blockIdx.x * 32, by = blockIdx.y * 32;
    int tx = threadIdx.x, ty = threadIdx.y;   // (32,8)
    for (int r = ty; r < 32; r += 8)
        tile[r][tx] = src[(size_t)(by + r) * 1024 + bx + tx];
    __syncthreads();
    for (int r = ty; r < 32; r += 8)
        dst[(size_t)(bx + r) * 1024 + by + tx] =
            (unsigned short)(__float_as_uint(tile[tx][r]) >> 16);
}

// ---------------- k_scalar: var -> lam = 0.1*softplus(var/(1+eps)); sums[1] = sum|z|^2 ----
__global__ void k_scalar(const float* __restrict__ zz, const float* __restrict__ mgp,
                         double* __restrict__ sums, float* __restrict__ lam) {
    int t = threadIdx.x;  // 1024
    double s2 = 0.0, sg = 0.0;
    for (int i = t; i < NROWS; i += 1024) { s2 += (double)zz[i]; sg += (double)mgp[i]; }
    __shared__ double l2[1024], lg[1024];
    l2[t] = s2; lg[t] = sg; __syncthreads();
    for (int s = 512; s > 0; s >>= 1) {
        if (t < s) { l2[t] += l2[t + s]; lg[t] += lg[t + s]; }
        __syncthreads();
    }
    if (t == 0) {
        double M = 16777216.0;
        double var = (l2[0] - lg[0] * lg[0] / M) / (M - 1.0);
        double x = var / (1.0 + 1e-6);
        double mod = log1p(exp(x));
        lam[0] = (float)(0.1 * mod);
        sums[1] = l2[0];
    }
}

// ---------------- shared m97-structure mainloop: 128x128 tile, 4 waves, 64x64/wave --------
// LDS tile [128 rows][64 cols] bf16, linear in 16B granules g = row*8 + slot.
// global_load_lds writes linearly; swizzle applied by fetching granule (r,s) from global
// column ((s ^ (r&7))<<3) and reading fragments at slot' = s ^ (r&7) (involution both sides).
__device__ __forceinline__ void gemm_mainloop(
    const unsigned short* __restrict__ Ap, const unsigned short* __restrict__ Bp,
    int row0, int col0, int wv, int ln,
    unsigned short* As, unsigned short* Bs, floatx4 (&acc)[4][4]) {
    int wr = (wv >> 1) * 64, wc = (wv & 1) * 64;
    size_t sa[4], sbo[4];
    int dst[4];
    #pragma unroll
    for (int j = 0; j < 4; ++j) {
        int g = j * 256 + wv * 64 + ln;        // granule index 0..1023 (per tile)
        int r = g >> 3, s0 = g & 7;
        size_t co = (size_t)((s0 ^ (r & 7)) << 3);
        sa[j]  = (size_t)(row0 + r) * KD + co;
        sbo[j] = (size_t)(col0 + r) * KD + co;
        dst[j] = (j * 256 + wv * 64) * 8;      // wave-uniform LDS dest (elements)
    }
    for (int kb = 0; kb < KD; kb += 64) {
        #pragma unroll
        for (int j = 0; j < 4; ++j) gload_lds16(Ap + sa[j] + kb, &As[dst[j]]);
        #pragma unroll
        for (int j = 0; j < 4; ++j) gload_lds16(Bp + sbo[j] + kb, &Bs[dst[j]]);
        __syncthreads();
        #pragma unroll
        for (int kk = 0; kk < 2; ++kk) {
            int sbi = kk * 4 + (ln >> 4);      // un-swizzled 16B slot of this fragment
            short8 af[4], bf[4];
            #pragma unroll
            for (int i = 0; i < 4; ++i) {
                int r = wr + i * 16 + (ln & 15);
                af[i] = *(const short8*)&As[r * 64 + ((sbi ^ (r & 7)) << 3)];
            }
            #pragma unroll
            for (int j = 0; j < 4; ++j) {
                int r = wc + j * 16 + (ln & 15);
                bf[j] = *(const short8*)&Bs[r * 64 + ((sbi ^ (r & 7)) << 3)];
            }
            #pragma unroll
            for (int mi = 0; mi < 4; ++mi)
                #pragma unroll
                for (int ni = 0; ni < 4; ++ni)
                    acc[mi][ni] = __builtin_amdgcn_mfma_f32_16x16x32_bf16(af[mi], bf[ni], acc[mi][ni], 0, 0, 0);
        }
        __syncthreads();
    }
}

// ---------------- k_gemm1: d1 = zb @ cb^T; write partial (cc - 2 d1)/1024 as fp16 ---------
__global__ __launch_bounds__(256, 4)
void k_gemm1(const unsigned short* __restrict__ zb,
             const unsigned short* __restrict__ cb_bf,
             const float* __restrict__ cc, _Float16* __restrict__ s_out) {
    __shared__ unsigned short As[128 * 64], Bs[128 * 64];
    int tid = threadIdx.x, bid = blockIdx.x;
    int wg = (bid & 7) * 256 + (bid >> 3);   // XCD-aware bijective remap (2048 % 8 == 0)
    int rt = wg >> 3, ct = wg & 7;
    int row0 = rt * 128, col0 = ct * 128;
    int wv = tid >> 6, ln = tid & 63;
    floatx4 acc[4][4];
    #pragma unroll
    for (int i = 0; i < 4; ++i)
        #pragma unroll
        for (int j = 0; j < 4; ++j) { floatx4 z4 = {0.f, 0.f, 0.f, 0.f}; acc[i][j] = z4; }
    gemm_mainloop(zb, cb_bf, row0, col0, wv, ln, As, Bs, acc);

    int wr = (wv >> 1) * 64, wc = (wv & 1) * 64;
    for (int mi = 0; mi < 4; ++mi) {
        int rbase = row0 + wr + mi * 16 + (ln >> 4) * 4;
        for (int ni = 0; ni < 4; ++ni) {
            int col = col0 + wc + ni * 16 + (ln & 15);
            float ccol = cc[col];
            for (int r2 = 0; r2 < 4; ++r2) {
                float sv = (ccol - 2.f * acc[mi][ni][r2]) * (1.0f / 1024.0f);
                s_out[(size_t)(rbase + r2) * KD + col] = (_Float16)sv;
            }
        }
    }
}

// ---------------- k_gemm2: d2 = pb @ adjT^T; s = partial - lam*sigmoid(d2); energy --------
__global__ __launch_bounds__(256, 4)
void k_gemm2(const unsigned short* __restrict__ pb,
             const unsigned short* __restrict__ adjT_bf,
             const float* __restrict__ lam_p,
             _Float16* __restrict__ s_io, double* __restrict__ e_acc) {
    __shared__ unsigned short As[128 * 64], Bs[128 * 64];
    int tid = threadIdx.x, bid = blockIdx.x;
    int wg = (bid & 7) * 256 + (bid >> 3);
    int rt = wg >> 3, ct = wg & 7;
    int row0 = rt * 128, col0 = ct * 128;
    int wv = tid >> 6, ln = tid & 63;
    floatx4 acc[4][4];
    #pragma unroll
    for (int i = 0; i < 4; ++i)
        #pragma unroll
        for (int j = 0; j < 4; ++j) { floatx4 z4 = {0.f, 0.f, 0.f, 0.f}; acc[i][j] = z4; }
    gemm_mainloop(pb, adjT_bf, row0, col0, wv, ln, As, Bs, acc);

    int wr = (wv >> 1) * 64, wc = (wv & 1) * 64;
    float lam = *lam_p;
    float esum = 0.f;
    for (int mi = 0; mi < 4; ++mi) {
        int rbase = row0 + wr + mi * 16 + (ln >> 4) * 4;
        for (int ni = 0; ni < 4; ++ni) {
            int col = col0 + wc + ni * 16 + (ln & 15);
            for (int r2 = 0; r2 < 4; ++r2) {
                size_t idx = (size_t)(rbase + r2) * KD + col;
                float sv = (float)s_io[idx] - lam / (1.f + __expf(-acc[mi][ni][r2]));
                esum += sv;
                s_io[idx] = (_Float16)sv;
            }
        }
    }
    for (int o = 32; o > 0; o >>= 1) esum += __shfl_down(esum, o);
    if (ln == 0) atomicAdd(e_acc, (double)esum);
}

// ---------------- k_softmax: probs = softmax(-s) rowwise; in-place fp16 -> bf16 -----------
__global__ void k_softmax(_Float16* __restrict__ sp) {
    int row = blockIdx.x, t = threadIdx.x;
    int wv = t >> 6, ln = t & 63;
    _Float16* srow = sp + (size_t)row * KD;
    h4 v = *(const h4*)(srow + t * 4);
    float x0 = -(float)v.x, x1 = -(float)v.y, x2 = -(float)v.z, x3 = -(float)v.w;
    float mx = fmaxf(fmaxf(x0, x1), fmaxf(x2, x3));
    for (int o = 1; o < 64; o <<= 1) mx = fmaxf(mx, __shfl_xor(mx, o));
    __shared__ float redm[4];
    if (ln == 0) redm[wv] = mx;
    __syncthreads();
    mx = fmaxf(fmaxf(redm[0], redm[1]), fmaxf(redm[2], redm[3]));
    float e0 = __expf(x0 - mx), e1 = __expf(x1 - mx), e2 = __expf(x2 - mx), e3 = __expf(x3 - mx);
    float ss = e0 + e1 + e2 + e3;
    for (int o = 1; o < 64; o <<= 1) ss += __shfl_xor(ss, o);
    __shared__ float reds[4];
    if (ln == 0) reds[wv] = ss;
    __syncthreads();
    ss = reds[0] + reds[1] + reds[2] + reds[3];
    float inv = 1.f / ss;
    unsigned p0 = __float_as_uint(e0 * inv), p1 = __float_as_uint(e1 * inv);
    unsigned p2 = __float_as_uint(e2 * inv), p3 = __float_as_uint(e3 * inv);
    *(uint2*)((unsigned short*)srow + t * 4) = make_uint2(pk_bf16(p1, p0), pk_bf16(p3, p2));
}

// ---------------- k_gemm3: z_q = probs @ codebook (via codebook^T), m97 structure ---------
__global__ __launch_bounds__(256, 4)
void k_gemm3(const unsigned short* __restrict__ probs,
             const unsigned short* __restrict__ cbT_bf,
             float* __restrict__ outR, float* __restrict__ outI) {
    __shared__ unsigned short As[128 * 64], Bs[128 * 64];
    int tid = threadIdx.x, bid = blockIdx.x;
    int wg = (bid & 7) * 256 + (bid >> 3);
    int rt = wg >> 3, ct = wg & 7;
    int row0 = rt * 128, col0 = ct * 128;
    int wv = tid >> 6, ln = tid & 63;
    floatx4 acc[4][4];
    #pragma unroll
    for (int i = 0; i < 4; ++i)
        #pragma unroll
        for (int j = 0; j < 4; ++j) { floatx4 z4 = {0.f, 0.f, 0.f, 0.f}; acc[i][j] = z4; }
    gemm_mainloop(probs, cbT_bf, row0, col0, wv, ln, As, Bs, acc);

    int wr = (wv >> 1) * 64, wc = (wv & 1) * 64;
    for (int mi = 0; mi < 4; ++mi) {
        int rbase = row0 + wr + mi * 16 + (ln >> 4) * 4;
        for (int ni = 0; ni < 4; ++ni) {
            int col = col0 + wc + ni * 16 + (ln & 15);
            for (int r2 = 0; r2 < 4; ++r2) {
                float v = acc[mi][ni][r2];
                size_t row = (size_t)(rbase + r2);
                if (col < DD) outR[row * DD + col] = v;
                else          outI[row * DD + (col - DD)] = v;
            }
        }
    }
}

// ---------------- k_final: energy = (sum_s + sum|z|^2) / (M*N) ----------------------------
__global__ void k_final(const double* __restrict__ sums, float* __restrict__ outE) {
    outE[0] = (float)((sums[0] + sums[1]) / 33554432.0);
}

extern "C" void kernel_launch(void* const* d_in, const int* in_sizes, int n_in,
                              void* d_out, int out_size, void* d_ws, size_t ws_size,
                              hipStream_t stream) {
    const float* zr   = (const float*)d_in[0];
    const float* zi   = (const float*)d_in[1];
    const float* prev = (const float*)d_in[2];
    const float* cb   = (const float*)d_in[3];
    const float* adj  = (const float*)d_in[4];
    float* out  = (float*)d_out;
    float* outR = out;
    float* outI = out + (size_t)16777216;
    float* outE = out + (size_t)33554432;

    // zb/pb live in d_out: consumed by k_gemm1/k_gemm2, dead before k_gemm3 overwrites d_out.
    unsigned short* zb = (unsigned short*)d_out;                        // [32768][1024] bf16
    unsigned short* pb = (unsigned short*)d_out + (size_t)33554432;     // [32768][1024] bf16

    char* ws = (char*)d_ws;
    double* sums          = (double*)ws;                       // [0]=energy acc, [1]=sum|z|^2
    float*  lam           = (float*)(ws + 16);
    float*  zz            = (float*)(ws + 256);                // [32768]
    float*  mgp           = (float*)(ws + 131328);             // [32768]
    float*  cc            = (float*)(ws + 262400);             // [1024]
    unsigned short* cb_bf = (unsigned short*)(ws + 266496);    // [1024*1024] bf16
    unsigned short* adjT  = (unsigned short*)(ws + 2363648);   // [1024*1024] bf16 (transposed)
    unsigned short* cbT   = (unsigned short*)(ws + 4460800);   // [1024*1024] bf16 (transposed)
    _Float16*       sbuf  = (_Float16*)(ws + 6557952);         // [32768*1024] fp16 logits -> bf16 probs

    hipMemsetAsync(d_ws, 0, 32, stream);
    k_row<<<32768, 256, 0, stream>>>(zr, zi, zb, zz, mgp);
    k_prev<<<16384, 256, 0, stream>>>(prev, pb);
    k_cb<<<1024, 256, 0, stream>>>(cb, cb_bf, cc);
    k_tr<<<dim3(32, 32), dim3(32, 8), 0, stream>>>(adj, adjT);
    k_tr<<<dim3(32, 32), dim3(32, 8), 0, stream>>>(cb, cbT);
    k_scalar<<<1, 1024, 0, stream>>>(zz, mgp, sums, lam);
    k_gemm1<<<2048, 256, 0, stream>>>(zb, cb_bf, cc, sbuf);
    k_gemm2<<<2048, 256, 0, stream>>>(pb, adjT, lam, sbuf, sums);
    k_softmax<<<32768, 256, 0, stream>>>(sbuf);
    k_gemm3<<<2048, 256, 0, stream>>>((const unsigned short*)sbuf, cbT, outR, outI);
    k_final<<<1, 1, 0, stream>>>(sums, outE);
}